// Round 12
// baseline (868.253 us; speedup 1.0000x reference)
//
#include <hip/hip_runtime.h>
#include <stdint.h>

#define S_ 512
#define B_ 64
#define V_ 50000
#define E_ 300
#define H_ 256
#define C_ 5

typedef _Float16 h8_t __attribute__((ext_vector_type(8)));
typedef float f32x4 __attribute__((ext_vector_type(4)));

// tanh(x) = 1 - 2/(e^{2x}+1); e^{2x}=2^{2x*log2e}. No clamp needed:
// x->-inf: e->0 -> -1; x->+inf: e->inf, rcp(inf)=0 -> +1.
__device__ __forceinline__ float fast_tanh(float x) {
    float e = __builtin_amdgcn_exp2f(x * 2.88539008177793f);  // 2*log2(e)
    return fmaf(-2.0f, __builtin_amdgcn_rcpf(e + 1.0f), 1.0f);
}

// ---------------------------------------------------------------------------
// Kernel A: pack W_ih (H,E) f32 -> WB f16 in B-fragment order for the xw GEMM.
// ---------------------------------------------------------------------------
__global__ void wb_prep_kernel(const float* __restrict__ W_ih,
                               uint4* __restrict__ WB) {
    int g = blockIdx.x * 256 + threadIdx.x;  // 0 .. 16*10*64-1
    if (g >= 16 * 10 * 64) return;
    int l = g & 63;
    int ks = (g >> 6) % 10;
    int nt = g / 640;
    int h = nt * 16 + (l & 15);
    int e0 = ks * 32 + (l >> 4) * 8;
    h8_t v;
#pragma unroll
    for (int j = 0; j < 8; ++j) {
        int e = e0 + j;
        v[j] = (e < E_) ? (_Float16)W_ih[(size_t)h * E_ + e] : (_Float16)0.0f;
    }
    WB[g] = __builtin_bit_cast(uint4, v);
}

// ---------------------------------------------------------------------------
// Kernel B: xw[s,b,h] = sum_e emb[idx[s,b],e]*W_ih[h,e] + b_ih[h] + b_hh[h]
// MFMA version: 512 blocks x 512 threads (8 waves). (R7 structure, ~25us)
// ---------------------------------------------------------------------------
__global__ __launch_bounds__(512, 2) void xw_kernel(
    const int* __restrict__ idx, const float* __restrict__ emb,
    const uint4* __restrict__ WB, const float* __restrict__ b_ih,
    const float* __restrict__ b_hh, float* __restrict__ xw) {
    __shared__ uint4 Afrag[4 * 10 * 64];
    const int tid = threadIdx.x;
    const int w = tid >> 6;  // wave 0..7
    const int l = tid & 63;
    const int n = l & 15;
    const int hi = l >> 4;
    const int base = blockIdx.x * 64;

    for (int cc = tid; cc < 64 * 40; cc += 512) {
        int m = cc / 40;
        int c = cc - m * 40;  // chunk: e = 8c..8c+7
        int ks = c >> 2;
        int hic = c & 3;
        const float* src = emb + (size_t)idx[base + m] * E_ + 8 * c;
        h8_t v;
        if (c < 37) {
            float4 f0 = *(const float4*)src;
            float4 f1 = *(const float4*)(src + 4);
            v[0] = (_Float16)f0.x; v[1] = (_Float16)f0.y;
            v[2] = (_Float16)f0.z; v[3] = (_Float16)f0.w;
            v[4] = (_Float16)f1.x; v[5] = (_Float16)f1.y;
            v[6] = (_Float16)f1.z; v[7] = (_Float16)f1.w;
        } else if (c == 37) {
            float4 f0 = *(const float4*)src;
            v[0] = (_Float16)f0.x; v[1] = (_Float16)f0.y;
            v[2] = (_Float16)f0.z; v[3] = (_Float16)f0.w;
            v[4] = (_Float16)0.0f; v[5] = (_Float16)0.0f;
            v[6] = (_Float16)0.0f; v[7] = (_Float16)0.0f;
        } else {
            v = (h8_t)(_Float16)0.0f;
        }
        int fl = (hic << 4) | (m & 15);
        int mt = m >> 4;
        Afrag[(mt * 10 + ks) * 64 + fl] = __builtin_bit_cast(uint4, v);
    }
    __syncthreads();

    float bias0 = b_ih[w * 32 + n] + b_hh[w * 32 + n];
    float bias1 = b_ih[w * 32 + 16 + n] + b_hh[w * 32 + 16 + n];
    f32x4 c[4][2];
#pragma unroll
    for (int mt = 0; mt < 4; ++mt) {
        c[mt][0] = (f32x4)bias0;
        c[mt][1] = (f32x4)bias1;
    }

    const uint4* wb0 = WB + ((2 * w) * 10) * 64 + l;
    const uint4* wb1 = WB + ((2 * w + 1) * 10) * 64 + l;
#pragma unroll
    for (int ks = 0; ks < 10; ++ks) {
        h8_t b0 = __builtin_bit_cast(h8_t, wb0[ks * 64]);
        h8_t b1 = __builtin_bit_cast(h8_t, wb1[ks * 64]);
#pragma unroll
        for (int mt = 0; mt < 4; ++mt) {
            h8_t a = __builtin_bit_cast(h8_t, Afrag[(mt * 10 + ks) * 64 + l]);
            c[mt][0] = __builtin_amdgcn_mfma_f32_16x16x32_f16(a, b0, c[mt][0],
                                                              0, 0, 0);
            c[mt][1] = __builtin_amdgcn_mfma_f32_16x16x32_f16(a, b1, c[mt][1],
                                                              0, 0, 0);
        }
    }

#pragma unroll
    for (int mt = 0; mt < 4; ++mt)
#pragma unroll
        for (int q = 0; q < 2; ++q) {
            float* op =
                xw + (size_t)(base + mt * 16 + hi * 4) * H_ + w * 32 + q * 16 + n;
#pragma unroll
            for (int r = 0; r < 4; ++r) op[(size_t)r * H_] = c[mt][q][r];
        }
}

// ---------------------------------------------------------------------------
// Kernel C: MFMA recurrence, HALF-SPLIT topology. 4 blocks x 16 batch cols,
// 512 threads (8 waves, 2 waves/SIMD).
//
// vs R8 (275us): waves 0-3 serve batch cols 0-7, waves 4-7 cols 8-15; each
// wave owns M=64 rows x N=8 real cols (A = 128 regs). Lanes n>=8 read the
// SAME LDS address as lane n-8 (broadcast = free) -> unique bytes per
// ds_read_b128 halve -> per-CU LDS B-read time ~770 -> ~400 cyc if the LDS
// pipe is bandwidth-limited (the hypothesis this round tests).
//
// R12 FIX vs R11 (absmax 45 failure): H'-write offset was missing the
// wave's row base. Row k0 = rowbase + mt*16 + hi*4 lives at byte
// (k0>>3)*128 = (wq*8 + mt*2 + (hi>>1))*128 — R11 omitted wq*8*128, so all
// 4 waves of a half wrote rows 0-63's region and rows 64-255 were garbage.
//
//   Per-half LDS layout (4KB per buffer-half), col c in 0..7:
//     byte(k, c) = (k>>3)*128 + c*16 + (k&7)*2
//   read:  lane l, slice ks -> b128 at (ks*4 + hi)*128 + (n&7)*16
//   write: lane (hi, n<8), tile mt -> b64 at
//          (wq*8 + mt*2 + (hi>>1))*128 + col*16 + (hi&1)*8
//
//   Light barrier (lgkmcnt only) + distance-2 xw prefetch into 4-slot cv
//   rotation (all indices compile-time). Dummy lanes (n>=8) duplicate col
//   n-8's C/D: harmless; H'/hsum writes masked to n<8.
// ---------------------------------------------------------------------------
__global__ __launch_bounds__(512, 2) void rnn_kernel(
    const float* __restrict__ xw, const float* __restrict__ W_hh,
    float* __restrict__ hsum_out) {
    const int tid = threadIdx.x;
    const int w = tid >> 6;    // wave 0..7
    const int l = tid & 63;
    const int n = l & 15;
    const int hi = l >> 4;
    const int half = w >> 2;   // 0: cols 0-7, 1: cols 8-15
    const int wq = w & 3;      // wave within half
    const int rowbase = wq * 64;
    const int col = n & 7;     // real col within half
    const int bbase = blockIdx.x * 16;
    const bool writer = (n < 8);

    __shared__ __attribute__((aligned(16))) unsigned char Hl[2][2][4096];
    char* lds = (char*)Hl;

    // ---- A fragments: W_hh rows rowbase..rowbase+63 as f16 (128 regs) ----
    h8_t a[4][8];
#pragma unroll
    for (int mt = 0; mt < 4; ++mt) {
        const float* wr = W_hh + (size_t)(rowbase + mt * 16 + n) * H_;
#pragma unroll
        for (int ks = 0; ks < 8; ++ks) {
            const float* wp = wr + ks * 32 + hi * 8;
            float4 f0 = *(const float4*)wp;
            float4 f1 = *(const float4*)(wp + 4);
            h8_t v;
            v[0] = (_Float16)f0.x; v[1] = (_Float16)f0.y;
            v[2] = (_Float16)f0.z; v[3] = (_Float16)f0.w;
            v[4] = (_Float16)f1.x; v[5] = (_Float16)f1.y;
            v[6] = (_Float16)f1.z; v[7] = (_Float16)f1.w;
            a[mt][ks] = v;
        }
    }

    // H'-write byte offsets (within a buffer): rows k0..k0+3, col
    // k0 = rowbase + mt*16 + hi*4  ->  (k0>>3)*128 + col*16 + (k0&7)*2
    int wboff[4];
#pragma unroll
    for (int mt = 0; mt < 4; ++mt) {
        wboff[mt] = half * 4096 + (wq * 8 + mt * 2 + (hi >> 1)) * 128 +
                    col * 16 + (hi & 1) * 8;
    }
    // B-read base (within a buffer): + ks*512
    const int rdbase = half * 4096 + col * 16 + hi * 128;

    // zero H buffer 0 (8 KB = 2048 dwords; zero both buffers for safety)
    for (int t = tid; t < 4096; t += 512) ((unsigned int*)Hl)[t] = 0u;

    f32x4 hs[4];
#pragma unroll
    for (int mt = 0; mt < 4; ++mt) hs[mt] = (f32x4)0.0f;

    // per-lane xw base: xw[s][bbase + half*8 + col][rowbase + mt*16 + hi*4 + r]
    const float* xwl =
        xw + (size_t)(bbase + half * 8 + col) * H_ + rowbase + hi * 4;
    // 4-slot rotation of xw-as-C-operand buffers (distance-2 prefetch)
    f32x4 cv[4][4];
#pragma unroll
    for (int mt = 0; mt < 4; ++mt) {
        cv[0][mt] = *(const f32x4*)(xwl + mt * 16);          // s = 0
        cv[1][mt] = *(const f32x4*)(xwl + 16384 + mt * 16);  // s = 1
    }
    __syncthreads();  // zero-init visible

#define STEP(CUR, I, SBASE)                                                    \
    {                                                                          \
        int sp = (SBASE) + 2;                                                  \
        if (sp > S_ - 1) sp = S_ - 1;                                          \
        _Pragma("unroll") for (int mt = 0; mt < 4; ++mt)                       \
            cv[(I + 2) & 3][mt] =                                              \
                *(const f32x4*)(xwl + (size_t)sp * 16384 + mt * 16);           \
        h8_t bf[8];                                                            \
        _Pragma("unroll") for (int ks = 0; ks < 8; ++ks)                       \
            bf[ks] = *(const h8_t*)(lds + (CUR)*8192 + rdbase + ks * 512);     \
        _Pragma("unroll") for (int ks = 0; ks < 8; ++ks) {                     \
            cv[I][0] = __builtin_amdgcn_mfma_f32_16x16x32_f16(                 \
                a[0][ks], bf[ks], cv[I][0], 0, 0, 0);                          \
            cv[I][1] = __builtin_amdgcn_mfma_f32_16x16x32_f16(                 \
                a[1][ks], bf[ks], cv[I][1], 0, 0, 0);                          \
            cv[I][2] = __builtin_amdgcn_mfma_f32_16x16x32_f16(                 \
                a[2][ks], bf[ks], cv[I][2], 0, 0, 0);                          \
            cv[I][3] = __builtin_amdgcn_mfma_f32_16x16x32_f16(                 \
                a[3][ks], bf[ks], cv[I][3], 0, 0, 0);                          \
        }                                                                      \
        _Pragma("unroll") for (int mt = 0; mt < 4; ++mt) {                     \
            float h0 = fast_tanh(cv[I][mt][0]);                                \
            float h1 = fast_tanh(cv[I][mt][1]);                                \
            float h2 = fast_tanh(cv[I][mt][2]);                                \
            float h3 = fast_tanh(cv[I][mt][3]);                                \
            hs[mt][0] += h0; hs[mt][1] += h1;                                  \
            hs[mt][2] += h2; hs[mt][3] += h3;                                  \
            if (writer) {                                                      \
                uint2 pk;                                                      \
                pk.x = __builtin_bit_cast(unsigned int,                        \
                                          __builtin_amdgcn_cvt_pkrtz(h0, h1)); \
                pk.y = __builtin_bit_cast(unsigned int,                        \
                                          __builtin_amdgcn_cvt_pkrtz(h2, h3)); \
                *(uint2*)(lds + ((CUR) ^ 1) * 8192 + wboff[mt]) = pk;          \
            }                                                                  \
        }                                                                      \
        asm volatile("s_waitcnt lgkmcnt(0)" ::: "memory");                     \
        __builtin_amdgcn_s_barrier();                                          \
    }

    for (int s = 0; s < S_; s += 4) {
        STEP(0, 0, s)
        STEP(1, 1, s + 1)
        STEP(0, 2, s + 2)
        STEP(1, 3, s + 3)
    }
#undef STEP

    if (writer) {
#pragma unroll
        for (int mt = 0; mt < 4; ++mt) {
            float4 o;
            o.x = hs[mt][0]; o.y = hs[mt][1];
            o.z = hs[mt][2]; o.w = hs[mt][3];
            *(float4*)(hsum_out + (size_t)(bbase + half * 8 + col) * H_ +
                       rowbase + mt * 16 + hi * 4) = o;
        }
    }
}

// ---------------------------------------------------------------------------
// Kernel D: summed logits = hsum @ W_out^T + S*b_out, then log_softmax.
// ---------------------------------------------------------------------------
__global__ void out_kernel(const float* __restrict__ hsum,
                           const float* __restrict__ W_out,
                           const float* __restrict__ b_out,
                           float* __restrict__ out) {
    int b = threadIdx.x;
    if (b >= B_) return;
    float logits[C_];
#pragma unroll
    for (int c = 0; c < C_; ++c) {
        float acc = 0.0f;
        for (int k = 0; k < H_; ++k)
            acc = fmaf(hsum[b * H_ + k], W_out[c * H_ + k], acc);
        logits[c] = acc + (float)S_ * b_out[c];
    }
    float m = logits[0];
#pragma unroll
    for (int c = 1; c < C_; ++c) m = fmaxf(m, logits[c]);
    float sum = 0.0f;
#pragma unroll
    for (int c = 0; c < C_; ++c) sum += expf(logits[c] - m);
    float lse = logf(sum);
#pragma unroll
    for (int c = 0; c < C_; ++c) out[b * C_ + c] = logits[c] - m - lse;
}

// ---------------------------------------------------------------------------
extern "C" void kernel_launch(void* const* d_in, const int* in_sizes, int n_in,
                              void* d_out, int out_size, void* d_ws,
                              size_t ws_size, hipStream_t stream) {
    const int* idx = (const int*)d_in[0];
    const float* emb = (const float*)d_in[1];
    const float* W_ih = (const float*)d_in[2];
    const float* W_hh = (const float*)d_in[3];
    const float* b_ih = (const float*)d_in[4];
    const float* b_hh = (const float*)d_in[5];
    const float* W_out = (const float*)d_in[6];
    const float* b_out = (const float*)d_in[7];
    float* out = (float*)d_out;

    float* ws = (float*)d_ws;
    uint4* WB = (uint4*)ws;                    // 16*10*64 uint4 = 160 KB
    float* xw = ws + 40960;                    // S*B*H floats
    float* hsum = xw + (size_t)S_ * B_ * H_;   // B*H floats

    hipLaunchKernelGGL(wb_prep_kernel, dim3(40), dim3(256), 0, stream, W_ih,
                       WB);
    hipLaunchKernelGGL(xw_kernel, dim3((S_ * B_) / 64), dim3(512), 0, stream,
                       idx, emb, WB, b_ih, b_hh, xw);
    hipLaunchKernelGGL(rnn_kernel, dim3(4), dim3(512), 0, stream, xw, W_hh,
                       hsum);
    hipLaunchKernelGGL(out_kernel, dim3(1), dim3(64), 0, stream, hsum, W_out,
                       b_out, out);
}

// Round 13
// 297.842 us; speedup vs baseline: 2.9151x; 2.9151x over previous
//
#include <hip/hip_runtime.h>
#include <stdint.h>

#define S_ 512
#define B_ 64
#define V_ 50000
#define E_ 300
#define H_ 256
#define C_ 5

typedef _Float16 h8_t __attribute__((ext_vector_type(8)));
typedef float f32x4 __attribute__((ext_vector_type(4)));

// tanh(x) = 1 - 2/(e^{2x}+1); e^{2x}=2^{2x*log2e}. No clamp needed:
// x->-inf: e->0 -> -1; x->+inf: e->inf, rcp(inf)=0 -> +1.
__device__ __forceinline__ float fast_tanh(float x) {
    float e = __builtin_amdgcn_exp2f(x * 2.88539008177793f);  // 2*log2(e)
    return fmaf(-2.0f, __builtin_amdgcn_rcpf(e + 1.0f), 1.0f);
}

// ---------------------------------------------------------------------------
// Kernel A: pack W_ih (H,E) f32 -> WB f16 in B-fragment order for the xw GEMM.
// ---------------------------------------------------------------------------
__global__ void wb_prep_kernel(const float* __restrict__ W_ih,
                               uint4* __restrict__ WB) {
    int g = blockIdx.x * 256 + threadIdx.x;  // 0 .. 16*10*64-1
    if (g >= 16 * 10 * 64) return;
    int l = g & 63;
    int ks = (g >> 6) % 10;
    int nt = g / 640;
    int h = nt * 16 + (l & 15);
    int e0 = ks * 32 + (l >> 4) * 8;
    h8_t v;
#pragma unroll
    for (int j = 0; j < 8; ++j) {
        int e = e0 + j;
        v[j] = (e < E_) ? (_Float16)W_ih[(size_t)h * E_ + e] : (_Float16)0.0f;
    }
    WB[g] = __builtin_bit_cast(uint4, v);
}

// ---------------------------------------------------------------------------
// Kernel B: xw[s,b,h] = sum_e emb[idx[s,b],e]*W_ih[h,e] + b_ih[h] + b_hh[h]
// MFMA version: 512 blocks x 512 threads (8 waves). (R7 structure, ~25us)
// ---------------------------------------------------------------------------
__global__ __launch_bounds__(512, 2) void xw_kernel(
    const int* __restrict__ idx, const float* __restrict__ emb,
    const uint4* __restrict__ WB, const float* __restrict__ b_ih,
    const float* __restrict__ b_hh, float* __restrict__ xw) {
    __shared__ uint4 Afrag[4 * 10 * 64];
    const int tid = threadIdx.x;
    const int w = tid >> 6;  // wave 0..7
    const int l = tid & 63;
    const int n = l & 15;
    const int hi = l >> 4;
    const int base = blockIdx.x * 64;

    for (int cc = tid; cc < 64 * 40; cc += 512) {
        int m = cc / 40;
        int c = cc - m * 40;  // chunk: e = 8c..8c+7
        int ks = c >> 2;
        int hic = c & 3;
        const float* src = emb + (size_t)idx[base + m] * E_ + 8 * c;
        h8_t v;
        if (c < 37) {
            float4 f0 = *(const float4*)src;
            float4 f1 = *(const float4*)(src + 4);
            v[0] = (_Float16)f0.x; v[1] = (_Float16)f0.y;
            v[2] = (_Float16)f0.z; v[3] = (_Float16)f0.w;
            v[4] = (_Float16)f1.x; v[5] = (_Float16)f1.y;
            v[6] = (_Float16)f1.z; v[7] = (_Float16)f1.w;
        } else if (c == 37) {
            float4 f0 = *(const float4*)src;
            v[0] = (_Float16)f0.x; v[1] = (_Float16)f0.y;
            v[2] = (_Float16)f0.z; v[3] = (_Float16)f0.w;
            v[4] = (_Float16)0.0f; v[5] = (_Float16)0.0f;
            v[6] = (_Float16)0.0f; v[7] = (_Float16)0.0f;
        } else {
            v = (h8_t)(_Float16)0.0f;
        }
        int fl = (hic << 4) | (m & 15);
        int mt = m >> 4;
        Afrag[(mt * 10 + ks) * 64 + fl] = __builtin_bit_cast(uint4, v);
    }
    __syncthreads();

    float bias0 = b_ih[w * 32 + n] + b_hh[w * 32 + n];
    float bias1 = b_ih[w * 32 + 16 + n] + b_hh[w * 32 + 16 + n];
    f32x4 c[4][2];
#pragma unroll
    for (int mt = 0; mt < 4; ++mt) {
        c[mt][0] = (f32x4)bias0;
        c[mt][1] = (f32x4)bias1;
    }

    const uint4* wb0 = WB + ((2 * w) * 10) * 64 + l;
    const uint4* wb1 = WB + ((2 * w + 1) * 10) * 64 + l;
#pragma unroll
    for (int ks = 0; ks < 10; ++ks) {
        h8_t b0 = __builtin_bit_cast(h8_t, wb0[ks * 64]);
        h8_t b1 = __builtin_bit_cast(h8_t, wb1[ks * 64]);
#pragma unroll
        for (int mt = 0; mt < 4; ++mt) {
            h8_t a = __builtin_bit_cast(h8_t, Afrag[(mt * 10 + ks) * 64 + l]);
            c[mt][0] = __builtin_amdgcn_mfma_f32_16x16x32_f16(a, b0, c[mt][0],
                                                              0, 0, 0);
            c[mt][1] = __builtin_amdgcn_mfma_f32_16x16x32_f16(a, b1, c[mt][1],
                                                              0, 0, 0);
        }
    }

#pragma unroll
    for (int mt = 0; mt < 4; ++mt)
#pragma unroll
        for (int q = 0; q < 2; ++q) {
            float* op =
                xw + (size_t)(base + mt * 16 + hi * 4) * H_ + w * 32 + q * 16 + n;
#pragma unroll
            for (int r = 0; r < 4; ++r) op[(size_t)r * H_] = c[mt][q][r];
        }
}

// ---------------------------------------------------------------------------
// Kernel C: MFMA recurrence, BROADCAST topology. 8 blocks x 8 batch cols,
// 512 threads (8 waves, 2 waves/SIMD).
//
// Clean A/B vs R8 (275us): per-wave work is IDENTICAL (2 M-tiles, A = 64
// regs, 16 MFMA/step, same epilogue) — the only change is the block now
// serves 8 batch cols instead of 16, so B-fragment lanes n>=8 read the SAME
// LDS address as lane n-8 (same-address broadcast). Unique bytes per
// ds_read_b128 halve (1024->512B); H'-writes halve (only n<8 writes).
// If the LDS pipe is bandwidth-limited (m134: 85B/cyc), per-CU read cost
// drops 768 -> ~384 cyc/step. If it's issue-limited, this is neutral and
// closes the branch (R8 = floor). R12's spill failure mode is avoided:
// register demand is exactly R8's (~160), no rpw=64 anywhere.
//
//   Per-buffer LDS layout (4KB), col c in 0..7, k in 0..255:
//     byte(k, c) = (k>>3)*128 + c*16 + (k&7)*2
//   read:  lane l (n=l&15, hi=l>>4, col=n&7), slice ks ->
//          b128 at (ks*4 + hi)*128 + col*16      [n, n+8 same addr]
//   write: lane (hi, n<8), tile mt: rows k0..k0+3, col n,
//          k0 = w*32 + mt*16 + hi*4 ->
//          b64 at (w*4 + mt*2 + (hi>>1))*128 + n*16 + (hi&1)*8
//
//   Light barrier (lgkmcnt only) + distance-2 xw prefetch into 4-slot cv
//   rotation (all indices compile-time).
// ---------------------------------------------------------------------------
__global__ __launch_bounds__(512, 2) void rnn_kernel(
    const float* __restrict__ xw, const float* __restrict__ W_hh,
    float* __restrict__ hsum_out) {
    const int tid = threadIdx.x;
    const int w = tid >> 6;  // wave 0..7, rows 32w..32w+31
    const int l = tid & 63;
    const int n = l & 15;    // A row / B col / C col (0..15)
    const int hi = l >> 4;   // k-group
    const int col = n & 7;   // real batch col within block
    const int bbase = blockIdx.x * 8;
    const int rowbase = w * 32;
    const bool writer = (n < 8);

    __shared__ __attribute__((aligned(16))) unsigned char Hl[2][4096];
    char* lds = (char*)Hl;

    // ---- A fragments: W_hh rows rowbase..rowbase+31 as f16 (64 regs) ----
    h8_t a[2][8];
#pragma unroll
    for (int mt = 0; mt < 2; ++mt) {
        const float* wr = W_hh + (size_t)(rowbase + mt * 16 + n) * H_;
#pragma unroll
        for (int ks = 0; ks < 8; ++ks) {
            const float* wp = wr + ks * 32 + hi * 8;
            float4 f0 = *(const float4*)wp;
            float4 f1 = *(const float4*)(wp + 4);
            h8_t v;
            v[0] = (_Float16)f0.x; v[1] = (_Float16)f0.y;
            v[2] = (_Float16)f0.z; v[3] = (_Float16)f0.w;
            v[4] = (_Float16)f1.x; v[5] = (_Float16)f1.y;
            v[6] = (_Float16)f1.z; v[7] = (_Float16)f1.w;
            a[mt][ks] = v;
        }
    }

    // H'-write byte offsets (buffer-relative): rows k0..k0+3, col n (n<8)
    // k0 = w*32 + mt*16 + hi*4: (k0>>3) = w*4 + mt*2 + (hi>>1); k0&7 = (hi&1)*4
    int wboff[2];
#pragma unroll
    for (int mt = 0; mt < 2; ++mt) {
        wboff[mt] = (w * 4 + mt * 2 + (hi >> 1)) * 128 + n * 16 + (hi & 1) * 8;
    }
    // B-read base (buffer-relative); full addr: CUR*4096 + rdbase + ks*512
    const int rdbase = hi * 128 + col * 16;

    // zero H buffer 0 (4 KB = 1024 dwords)
    for (int t = tid; t < 1024; t += 512) ((unsigned int*)Hl)[t] = 0u;

    f32x4 hs[2];
    hs[0] = (f32x4)0.0f;
    hs[1] = (f32x4)0.0f;

    // per-lane xw base: xw[s][bbase+col][rowbase + mt*16 + hi*4 + r]
    const float* xwl = xw + (size_t)(bbase + col) * H_ + rowbase + hi * 4;
    // 4-slot rotation of xw-as-C-operand buffers (distance-2 prefetch)
    f32x4 cv[4][2];
    cv[0][0] = *(const f32x4*)(xwl);                  // s = 0
    cv[0][1] = *(const f32x4*)(xwl + 16);
    cv[1][0] = *(const f32x4*)(xwl + 16384);          // s = 1
    cv[1][1] = *(const f32x4*)(xwl + 16384 + 16);
    __syncthreads();  // zero-init visible

#define STEP(CUR, I, SBASE)                                                    \
    {                                                                          \
        int sp = (SBASE) + 2;                                                  \
        if (sp > S_ - 1) sp = S_ - 1;                                          \
        cv[(I + 2) & 3][0] = *(const f32x4*)(xwl + (size_t)sp * 16384);        \
        cv[(I + 2) & 3][1] = *(const f32x4*)(xwl + (size_t)sp * 16384 + 16);   \
        h8_t bf[8];                                                            \
        _Pragma("unroll") for (int ks = 0; ks < 8; ++ks)                       \
            bf[ks] = *(const h8_t*)(lds + (CUR)*4096 + rdbase + ks * 512);     \
        _Pragma("unroll") for (int ks = 0; ks < 8; ++ks) {                     \
            cv[I][0] = __builtin_amdgcn_mfma_f32_16x16x32_f16(                 \
                a[0][ks], bf[ks], cv[I][0], 0, 0, 0);                          \
            cv[I][1] = __builtin_amdgcn_mfma_f32_16x16x32_f16(                 \
                a[1][ks], bf[ks], cv[I][1], 0, 0, 0);                          \
        }                                                                      \
        _Pragma("unroll") for (int mt = 0; mt < 2; ++mt) {                     \
            float h0 = fast_tanh(cv[I][mt][0]);                                \
            float h1 = fast_tanh(cv[I][mt][1]);                                \
            float h2 = fast_tanh(cv[I][mt][2]);                                \
            float h3 = fast_tanh(cv[I][mt][3]);                                \
            hs[mt][0] += h0; hs[mt][1] += h1;                                  \
            hs[mt][2] += h2; hs[mt][3] += h3;                                  \
            if (writer) {                                                      \
                uint2 pk;                                                      \
                pk.x = __builtin_bit_cast(unsigned int,                        \
                                          __builtin_amdgcn_cvt_pkrtz(h0, h1)); \
                pk.y = __builtin_bit_cast(unsigned int,                        \
                                          __builtin_amdgcn_cvt_pkrtz(h2, h3)); \
                *(uint2*)(lds + ((CUR) ^ 1) * 4096 + wboff[mt]) = pk;          \
            }                                                                  \
        }                                                                      \
        asm volatile("s_waitcnt lgkmcnt(0)" ::: "memory");                     \
        __builtin_amdgcn_s_barrier();                                          \
    }

    for (int s = 0; s < S_; s += 4) {
        STEP(0, 0, s)
        STEP(1, 1, s + 1)
        STEP(0, 2, s + 2)
        STEP(1, 3, s + 3)
    }
#undef STEP

    if (writer) {
#pragma unroll
        for (int mt = 0; mt < 2; ++mt) {
            float4 o;
            o.x = hs[mt][0]; o.y = hs[mt][1];
            o.z = hs[mt][2]; o.w = hs[mt][3];
            *(float4*)(hsum_out + (size_t)(bbase + col) * H_ + rowbase +
                       mt * 16 + hi * 4) = o;
        }
    }
}

// ---------------------------------------------------------------------------
// Kernel D: summed logits = hsum @ W_out^T + S*b_out, then log_softmax.
// ---------------------------------------------------------------------------
__global__ void out_kernel(const float* __restrict__ hsum,
                           const float* __restrict__ W_out,
                           const float* __restrict__ b_out,
                           float* __restrict__ out) {
    int b = threadIdx.x;
    if (b >= B_) return;
    float logits[C_];
#pragma unroll
    for (int c = 0; c < C_; ++c) {
        float acc = 0.0f;
        for (int k = 0; k < H_; ++k)
            acc = fmaf(hsum[b * H_ + k], W_out[c * H_ + k], acc);
        logits[c] = acc + (float)S_ * b_out[c];
    }
    float m = logits[0];
#pragma unroll
    for (int c = 1; c < C_; ++c) m = fmaxf(m, logits[c]);
    float sum = 0.0f;
#pragma unroll
    for (int c = 0; c < C_; ++c) sum += expf(logits[c] - m);
    float lse = logf(sum);
#pragma unroll
    for (int c = 0; c < C_; ++c) out[b * C_ + c] = logits[c] - m - lse;
}

// ---------------------------------------------------------------------------
extern "C" void kernel_launch(void* const* d_in, const int* in_sizes, int n_in,
                              void* d_out, int out_size, void* d_ws,
                              size_t ws_size, hipStream_t stream) {
    const int* idx = (const int*)d_in[0];
    const float* emb = (const float*)d_in[1];
    const float* W_ih = (const float*)d_in[2];
    const float* W_hh = (const float*)d_in[3];
    const float* b_ih = (const float*)d_in[4];
    const float* b_hh = (const float*)d_in[5];
    const float* W_out = (const float*)d_in[6];
    const float* b_out = (const float*)d_in[7];
    float* out = (float*)d_out;

    float* ws = (float*)d_ws;
    uint4* WB = (uint4*)ws;                    // 16*10*64 uint4 = 160 KB
    float* xw = ws + 40960;                    // S*B*H floats
    float* hsum = xw + (size_t)S_ * B_ * H_;   // B*H floats

    hipLaunchKernelGGL(wb_prep_kernel, dim3(40), dim3(256), 0, stream, W_ih,
                       WB);
    hipLaunchKernelGGL(xw_kernel, dim3((S_ * B_) / 64), dim3(512), 0, stream,
                       idx, emb, WB, b_ih, b_hh, xw);
    hipLaunchKernelGGL(rnn_kernel, dim3(8), dim3(512), 0, stream, xw, W_hh,
                       hsum);
    hipLaunchKernelGGL(out_kernel, dim3(1), dim3(64), 0, stream, hsum, W_out,
                       b_out, out);
}

// Round 14
// 281.354 us; speedup vs baseline: 3.0860x; 1.0586x over previous
//
#include <hip/hip_runtime.h>
#include <stdint.h>

#define S_ 512
#define B_ 64
#define V_ 50000
#define E_ 300
#define H_ 256
#define C_ 5

typedef _Float16 h8_t __attribute__((ext_vector_type(8)));
typedef float f32x4 __attribute__((ext_vector_type(4)));

// tanh(x) = 1 - 2/(e^{2x}+1); e^{2x}=2^{2x*log2e}. No clamp needed:
// x->-inf: e->0 -> -1; x->+inf: e->inf, rcp(inf)=0 -> +1.
__device__ __forceinline__ float fast_tanh(float x) {
    float e = __builtin_amdgcn_exp2f(x * 2.88539008177793f);  // 2*log2(e)
    return fmaf(-2.0f, __builtin_amdgcn_rcpf(e + 1.0f), 1.0f);
}

// ---------------------------------------------------------------------------
// Kernel A: pack W_ih (H,E) f32 -> WB f16 in B-fragment order for the xw GEMM.
// ---------------------------------------------------------------------------
__global__ void wb_prep_kernel(const float* __restrict__ W_ih,
                               uint4* __restrict__ WB) {
    int g = blockIdx.x * 256 + threadIdx.x;  // 0 .. 16*10*64-1
    if (g >= 16 * 10 * 64) return;
    int l = g & 63;
    int ks = (g >> 6) % 10;
    int nt = g / 640;
    int h = nt * 16 + (l & 15);
    int e0 = ks * 32 + (l >> 4) * 8;
    h8_t v;
#pragma unroll
    for (int j = 0; j < 8; ++j) {
        int e = e0 + j;
        v[j] = (e < E_) ? (_Float16)W_ih[(size_t)h * E_ + e] : (_Float16)0.0f;
    }
    WB[g] = __builtin_bit_cast(uint4, v);
}

// ---------------------------------------------------------------------------
// Kernel B: xw[s,b,h] = sum_e emb[idx[s,b],e]*W_ih[h,e] + b_ih[h] + b_hh[h]
// MFMA version: 512 blocks x 512 threads (8 waves). (R7 structure, ~25us)
// ---------------------------------------------------------------------------
__global__ __launch_bounds__(512, 2) void xw_kernel(
    const int* __restrict__ idx, const float* __restrict__ emb,
    const uint4* __restrict__ WB, const float* __restrict__ b_ih,
    const float* __restrict__ b_hh, float* __restrict__ xw) {
    __shared__ uint4 Afrag[4 * 10 * 64];
    const int tid = threadIdx.x;
    const int w = tid >> 6;  // wave 0..7
    const int l = tid & 63;
    const int n = l & 15;
    const int hi = l >> 4;
    const int base = blockIdx.x * 64;

    for (int cc = tid; cc < 64 * 40; cc += 512) {
        int m = cc / 40;
        int c = cc - m * 40;  // chunk: e = 8c..8c+7
        int ks = c >> 2;
        int hic = c & 3;
        const float* src = emb + (size_t)idx[base + m] * E_ + 8 * c;
        h8_t v;
        if (c < 37) {
            float4 f0 = *(const float4*)src;
            float4 f1 = *(const float4*)(src + 4);
            v[0] = (_Float16)f0.x; v[1] = (_Float16)f0.y;
            v[2] = (_Float16)f0.z; v[3] = (_Float16)f0.w;
            v[4] = (_Float16)f1.x; v[5] = (_Float16)f1.y;
            v[6] = (_Float16)f1.z; v[7] = (_Float16)f1.w;
        } else if (c == 37) {
            float4 f0 = *(const float4*)src;
            v[0] = (_Float16)f0.x; v[1] = (_Float16)f0.y;
            v[2] = (_Float16)f0.z; v[3] = (_Float16)f0.w;
            v[4] = (_Float16)0.0f; v[5] = (_Float16)0.0f;
            v[6] = (_Float16)0.0f; v[7] = (_Float16)0.0f;
        } else {
            v = (h8_t)(_Float16)0.0f;
        }
        int fl = (hic << 4) | (m & 15);
        int mt = m >> 4;
        Afrag[(mt * 10 + ks) * 64 + fl] = __builtin_bit_cast(uint4, v);
    }
    __syncthreads();

    float bias0 = b_ih[w * 32 + n] + b_hh[w * 32 + n];
    float bias1 = b_ih[w * 32 + 16 + n] + b_hh[w * 32 + 16 + n];
    f32x4 c[4][2];
#pragma unroll
    for (int mt = 0; mt < 4; ++mt) {
        c[mt][0] = (f32x4)bias0;
        c[mt][1] = (f32x4)bias1;
    }

    const uint4* wb0 = WB + ((2 * w) * 10) * 64 + l;
    const uint4* wb1 = WB + ((2 * w + 1) * 10) * 64 + l;
#pragma unroll
    for (int ks = 0; ks < 10; ++ks) {
        h8_t b0 = __builtin_bit_cast(h8_t, wb0[ks * 64]);
        h8_t b1 = __builtin_bit_cast(h8_t, wb1[ks * 64]);
#pragma unroll
        for (int mt = 0; mt < 4; ++mt) {
            h8_t a = __builtin_bit_cast(h8_t, Afrag[(mt * 10 + ks) * 64 + l]);
            c[mt][0] = __builtin_amdgcn_mfma_f32_16x16x32_f16(a, b0, c[mt][0],
                                                              0, 0, 0);
            c[mt][1] = __builtin_amdgcn_mfma_f32_16x16x32_f16(a, b1, c[mt][1],
                                                              0, 0, 0);
        }
    }

#pragma unroll
    for (int mt = 0; mt < 4; ++mt)
#pragma unroll
        for (int q = 0; q < 2; ++q) {
            float* op =
                xw + (size_t)(base + mt * 16 + hi * 4) * H_ + w * 32 + q * 16 + n;
#pragma unroll
            for (int r = 0; r < 4; ++r) op[(size_t)r * H_] = c[mt][q][r];
        }
}

// ---------------------------------------------------------------------------
// Kernel C: MFMA recurrence, BROADCAST topology + SPLIT EPILOGUE.
// 8 blocks x 8 batch cols, 512 threads (8 waves, 2 waves/SIMD).
//
// R13 (247us) insight: lanes n and n+8 hold IDENTICAL cv values (duplicate
// B cols) and both ran the full 8-tanh epilogue (half discarded). R14: the
// pair splits the work — lane n (n<8) processes TILE 0's 4 values, lane
// n+8 processes TILE 1's. Select via vector ternary (cndmask, no runtime
// array index); each lane: 4 tanh, 2 cvt_pk, 1 ds_write_b64, 1 hsum f32x4.
// Per-wave epilogue cost halves (~96cyc/wave/step: 8 trans@8 + ~16 VALU@2);
// coverage: 64 lanes x 4 = 32 rows x 8 cols, each exactly once.
// MFMA/LDS-read/barrier structure byte-identical to R13 (clean A/B).
//
//   Per-buffer LDS layout (4KB), col c in 0..7, k in 0..255:
//     byte(k, c) = (k>>3)*128 + c*16 + (k&7)*2
//   read:  lane l (n=l&15, hi=l>>4, col=n&7), slice ks ->
//          b128 at (ks*4 + hi)*128 + col*16      [n, n+8 same addr]
//   write: lane (hi,n), tile sel=n>>3: rows k0..k0+3, col,
//          k0 = w*32 + sel*16 + hi*4 ->
//          b64 at (w*4 + sel*2 + (hi>>1))*128 + col*16 + (hi&1)*8
//
//   Light barrier (lgkmcnt only) + distance-2 xw prefetch into 4-slot cv
//   rotation (all indices compile-time).
// ---------------------------------------------------------------------------
__global__ __launch_bounds__(512, 2) void rnn_kernel(
    const float* __restrict__ xw, const float* __restrict__ W_hh,
    float* __restrict__ hsum_out) {
    const int tid = threadIdx.x;
    const int w = tid >> 6;  // wave 0..7, rows 32w..32w+31
    const int l = tid & 63;
    const int n = l & 15;    // A row / B col / C col (0..15)
    const int hi = l >> 4;   // k-group
    const int col = n & 7;   // real batch col within block
    const int sel = n >> 3;  // epilogue tile handled by this lane (0 or 1)
    const int bbase = blockIdx.x * 8;
    const int rowbase = w * 32;

    __shared__ __attribute__((aligned(16))) unsigned char Hl[2][4096];
    char* lds = (char*)Hl;

    // ---- A fragments: W_hh rows rowbase..rowbase+31 as f16 (64 regs) ----
    h8_t a[2][8];
#pragma unroll
    for (int mt = 0; mt < 2; ++mt) {
        const float* wr = W_hh + (size_t)(rowbase + mt * 16 + n) * H_;
#pragma unroll
        for (int ks = 0; ks < 8; ++ks) {
            const float* wp = wr + ks * 32 + hi * 8;
            float4 f0 = *(const float4*)wp;
            float4 f1 = *(const float4*)(wp + 4);
            h8_t v;
            v[0] = (_Float16)f0.x; v[1] = (_Float16)f0.y;
            v[2] = (_Float16)f0.z; v[3] = (_Float16)f0.w;
            v[4] = (_Float16)f1.x; v[5] = (_Float16)f1.y;
            v[6] = (_Float16)f1.z; v[7] = (_Float16)f1.w;
            a[mt][ks] = v;
        }
    }

    // H'-write byte offset (buffer-relative): tile sel, rows k0..k0+3, col
    // k0 = w*32 + sel*16 + hi*4
    const int wboff =
        (w * 4 + sel * 2 + (hi >> 1)) * 128 + col * 16 + (hi & 1) * 8;
    // B-read base (buffer-relative); full addr: CUR*4096 + rdbase + ks*512
    const int rdbase = hi * 128 + col * 16;

    // zero H buffer 0 (4 KB = 1024 dwords)
    for (int t = tid; t < 1024; t += 512) ((unsigned int*)Hl)[t] = 0u;

    f32x4 hs = (f32x4)0.0f;  // running sum for this lane's tile (sel)

    // per-lane xw base: xw[s][bbase+col][rowbase + mt*16 + hi*4 + r]
    const float* xwl = xw + (size_t)(bbase + col) * H_ + rowbase + hi * 4;
    // 4-slot rotation of xw-as-C-operand buffers (distance-2 prefetch)
    f32x4 cv[4][2];
    cv[0][0] = *(const f32x4*)(xwl);                  // s = 0
    cv[0][1] = *(const f32x4*)(xwl + 16);
    cv[1][0] = *(const f32x4*)(xwl + 16384);          // s = 1
    cv[1][1] = *(const f32x4*)(xwl + 16384 + 16);
    __syncthreads();  // zero-init visible

#define STEP(CUR, I, SBASE)                                                    \
    {                                                                          \
        int sp = (SBASE) + 2;                                                  \
        if (sp > S_ - 1) sp = S_ - 1;                                          \
        cv[(I + 2) & 3][0] = *(const f32x4*)(xwl + (size_t)sp * 16384);        \
        cv[(I + 2) & 3][1] = *(const f32x4*)(xwl + (size_t)sp * 16384 + 16);   \
        h8_t bf[8];                                                            \
        _Pragma("unroll") for (int ks = 0; ks < 8; ++ks)                       \
            bf[ks] = *(const h8_t*)(lds + (CUR)*4096 + rdbase + ks * 512);     \
        _Pragma("unroll") for (int ks = 0; ks < 8; ++ks) {                     \
            cv[I][0] = __builtin_amdgcn_mfma_f32_16x16x32_f16(                 \
                a[0][ks], bf[ks], cv[I][0], 0, 0, 0);                          \
            cv[I][1] = __builtin_amdgcn_mfma_f32_16x16x32_f16(                 \
                a[1][ks], bf[ks], cv[I][1], 0, 0, 0);                          \
        }                                                                      \
        {                                                                      \
            f32x4 sv = (sel == 0) ? cv[I][0] : cv[I][1];                       \
            float h0 = fast_tanh(sv[0]);                                       \
            float h1 = fast_tanh(sv[1]);                                       \
            float h2 = fast_tanh(sv[2]);                                       \
            float h3 = fast_tanh(sv[3]);                                       \
            hs[0] += h0; hs[1] += h1; hs[2] += h2; hs[3] += h3;                \
            uint2 pk;                                                          \
            pk.x = __builtin_bit_cast(unsigned int,                            \
                                      __builtin_amdgcn_cvt_pkrtz(h0, h1));     \
            pk.y = __builtin_bit_cast(unsigned int,                            \
                                      __builtin_amdgcn_cvt_pkrtz(h2, h3));     \
            *(uint2*)(lds + ((CUR) ^ 1) * 4096 + wboff) = pk;                  \
        }                                                                      \
        asm volatile("s_waitcnt lgkmcnt(0)" ::: "memory");                     \
        __builtin_amdgcn_s_barrier();                                          \
    }

    for (int s = 0; s < S_; s += 4) {
        STEP(0, 0, s)
        STEP(1, 1, s + 1)
        STEP(0, 2, s + 2)
        STEP(1, 3, s + 3)
    }
#undef STEP

    // lane writes its tile's rows: rowbase + sel*16 + hi*4 .. +3, col
    {
        float4 o;
        o.x = hs[0]; o.y = hs[1]; o.z = hs[2]; o.w = hs[3];
        *(float4*)(hsum_out + (size_t)(bbase + col) * H_ + rowbase + sel * 16 +
                   hi * 4) = o;
    }
}

// ---------------------------------------------------------------------------
// Kernel D: summed logits = hsum @ W_out^T + S*b_out, then log_softmax.
// ---------------------------------------------------------------------------
__global__ void out_kernel(const float* __restrict__ hsum,
                           const float* __restrict__ W_out,
                           const float* __restrict__ b_out,
                           float* __restrict__ out) {
    int b = threadIdx.x;
    if (b >= B_) return;
    float logits[C_];
#pragma unroll
    for (int c = 0; c < C_; ++c) {
        float acc = 0.0f;
        for (int k = 0; k < H_; ++k)
            acc = fmaf(hsum[b * H_ + k], W_out[c * H_ + k], acc);
        logits[c] = acc + (float)S_ * b_out[c];
    }
    float m = logits[0];
#pragma unroll
    for (int c = 1; c < C_; ++c) m = fmaxf(m, logits[c]);
    float sum = 0.0f;
#pragma unroll
    for (int c = 0; c < C_; ++c) sum += expf(logits[c] - m);
    float lse = logf(sum);
#pragma unroll
    for (int c = 0; c < C_; ++c) out[b * C_ + c] = logits[c] - m - lse;
}

// ---------------------------------------------------------------------------
extern "C" void kernel_launch(void* const* d_in, const int* in_sizes, int n_in,
                              void* d_out, int out_size, void* d_ws,
                              size_t ws_size, hipStream_t stream) {
    const int* idx = (const int*)d_in[0];
    const float* emb = (const float*)d_in[1];
    const float* W_ih = (const float*)d_in[2];
    const float* W_hh = (const float*)d_in[3];
    const float* b_ih = (const float*)d_in[4];
    const float* b_hh = (const float*)d_in[5];
    const float* W_out = (const float*)d_in[6];
    const float* b_out = (const float*)d_in[7];
    float* out = (float*)d_out;

    float* ws = (float*)d_ws;
    uint4* WB = (uint4*)ws;                    // 16*10*64 uint4 = 160 KB
    float* xw = ws + 40960;                    // S*B*H floats
    float* hsum = xw + (size_t)S_ * B_ * H_;   // B*H floats

    hipLaunchKernelGGL(wb_prep_kernel, dim3(40), dim3(256), 0, stream, W_ih,
                       WB);
    hipLaunchKernelGGL(xw_kernel, dim3((S_ * B_) / 64), dim3(512), 0, stream,
                       idx, emb, WB, b_ih, b_hh, xw);
    hipLaunchKernelGGL(rnn_kernel, dim3(8), dim3(512), 0, stream, xw, W_hh,
                       hsum);
    hipLaunchKernelGGL(out_kernel, dim3(1), dim3(64), 0, stream, hsum, W_out,
                       b_out, out);
}

// Round 15
// 276.883 us; speedup vs baseline: 3.1358x; 1.0161x over previous
//
#include <hip/hip_runtime.h>
#include <stdint.h>

#define S_ 512
#define B_ 64
#define V_ 50000
#define E_ 300
#define H_ 256
#define C_ 5

typedef _Float16 h8_t __attribute__((ext_vector_type(8)));
typedef float f32x4 __attribute__((ext_vector_type(4)));

// tanh(x) = 1 - 2/(e^{2x}+1); e^{2x}=2^{2x*log2e}. No clamp needed:
// x->-inf: e->0 -> -1; x->+inf: e->inf, rcp(inf)=0 -> +1.
__device__ __forceinline__ float fast_tanh(float x) {
    float e = __builtin_amdgcn_exp2f(x * 2.88539008177793f);  // 2*log2(e)
    return fmaf(-2.0f, __builtin_amdgcn_rcpf(e + 1.0f), 1.0f);
}

// ---------------------------------------------------------------------------
// Kernel A: pack W_ih (H,E) f32 -> WB f16 in B-fragment order for the xw GEMM.
// ---------------------------------------------------------------------------
__global__ void wb_prep_kernel(const float* __restrict__ W_ih,
                               uint4* __restrict__ WB) {
    int g = blockIdx.x * 256 + threadIdx.x;  // 0 .. 16*10*64-1
    if (g >= 16 * 10 * 64) return;
    int l = g & 63;
    int ks = (g >> 6) % 10;
    int nt = g / 640;
    int h = nt * 16 + (l & 15);
    int e0 = ks * 32 + (l >> 4) * 8;
    h8_t v;
#pragma unroll
    for (int j = 0; j < 8; ++j) {
        int e = e0 + j;
        v[j] = (e < E_) ? (_Float16)W_ih[(size_t)h * E_ + e] : (_Float16)0.0f;
    }
    WB[g] = __builtin_bit_cast(uint4, v);
}

// ---------------------------------------------------------------------------
// Kernel B: xw[s,b,h] = sum_e emb[idx[s,b],e]*W_ih[h,e] + b_ih[h] + b_hh[h]
// MFMA version: 512 blocks x 512 threads (8 waves). (R7 structure, ~25us)
// ---------------------------------------------------------------------------
__global__ __launch_bounds__(512, 2) void xw_kernel(
    const int* __restrict__ idx, const float* __restrict__ emb,
    const uint4* __restrict__ WB, const float* __restrict__ b_ih,
    const float* __restrict__ b_hh, float* __restrict__ xw) {
    __shared__ uint4 Afrag[4 * 10 * 64];
    const int tid = threadIdx.x;
    const int w = tid >> 6;  // wave 0..7
    const int l = tid & 63;
    const int n = l & 15;
    const int hi = l >> 4;
    const int base = blockIdx.x * 64;

    for (int cc = tid; cc < 64 * 40; cc += 512) {
        int m = cc / 40;
        int c = cc - m * 40;  // chunk: e = 8c..8c+7
        int ks = c >> 2;
        int hic = c & 3;
        const float* src = emb + (size_t)idx[base + m] * E_ + 8 * c;
        h8_t v;
        if (c < 37) {
            float4 f0 = *(const float4*)src;
            float4 f1 = *(const float4*)(src + 4);
            v[0] = (_Float16)f0.x; v[1] = (_Float16)f0.y;
            v[2] = (_Float16)f0.z; v[3] = (_Float16)f0.w;
            v[4] = (_Float16)f1.x; v[5] = (_Float16)f1.y;
            v[6] = (_Float16)f1.z; v[7] = (_Float16)f1.w;
        } else if (c == 37) {
            float4 f0 = *(const float4*)src;
            v[0] = (_Float16)f0.x; v[1] = (_Float16)f0.y;
            v[2] = (_Float16)f0.z; v[3] = (_Float16)f0.w;
            v[4] = (_Float16)0.0f; v[5] = (_Float16)0.0f;
            v[6] = (_Float16)0.0f; v[7] = (_Float16)0.0f;
        } else {
            v = (h8_t)(_Float16)0.0f;
        }
        int fl = (hic << 4) | (m & 15);
        int mt = m >> 4;
        Afrag[(mt * 10 + ks) * 64 + fl] = __builtin_bit_cast(uint4, v);
    }
    __syncthreads();

    float bias0 = b_ih[w * 32 + n] + b_hh[w * 32 + n];
    float bias1 = b_ih[w * 32 + 16 + n] + b_hh[w * 32 + 16 + n];
    f32x4 c[4][2];
#pragma unroll
    for (int mt = 0; mt < 4; ++mt) {
        c[mt][0] = (f32x4)bias0;
        c[mt][1] = (f32x4)bias1;
    }

    const uint4* wb0 = WB + ((2 * w) * 10) * 64 + l;
    const uint4* wb1 = WB + ((2 * w + 1) * 10) * 64 + l;
#pragma unroll
    for (int ks = 0; ks < 10; ++ks) {
        h8_t b0 = __builtin_bit_cast(h8_t, wb0[ks * 64]);
        h8_t b1 = __builtin_bit_cast(h8_t, wb1[ks * 64]);
#pragma unroll
        for (int mt = 0; mt < 4; ++mt) {
            h8_t a = __builtin_bit_cast(h8_t, Afrag[(mt * 10 + ks) * 64 + l]);
            c[mt][0] = __builtin_amdgcn_mfma_f32_16x16x32_f16(a, b0, c[mt][0],
                                                              0, 0, 0);
            c[mt][1] = __builtin_amdgcn_mfma_f32_16x16x32_f16(a, b1, c[mt][1],
                                                              0, 0, 0);
        }
    }

#pragma unroll
    for (int mt = 0; mt < 4; ++mt)
#pragma unroll
        for (int q = 0; q < 2; ++q) {
            float* op =
                xw + (size_t)(base + mt * 16 + hi * 4) * H_ + w * 32 + q * 16 + n;
#pragma unroll
            for (int r = 0; r < 4; ++r) op[(size_t)r * H_] = c[mt][q][r];
        }
}

// ---------------------------------------------------------------------------
// Kernel C: MFMA recurrence, BROADCAST-4 topology + 4-WAY SPLIT EPILOGUE.
// 16 blocks x 4 batch cols, 512 threads (8 waves, 2 waves/SIMD).
//
// The R13/R14 knob turned once more: block batch-width 8 -> 4. Lane quads
// {n, n+4, n+8, n+12} read the SAME LDS address (4-way broadcast, <=2
// unique addrs/bank = free); unique bytes per ds_read_b128 halve again
// (512->256). Epilogue splits 4 ways across the quad (dup d = n>>2): lane
// handles tile t=d>>1, pair p=d&1 -> 2 tanh, 1 cvt_pk, 1 ds_write_b32,
// float2 hsum. Per-CU tanh work halves; 16 CUs active. MFMA per wave
// unchanged (16/step). Registers unchanged (~72; A = 64 regs).
//
//   Per-buffer LDS layout (2KB), col c in 0..3, k in 0..255:
//     byte(k, c) = (k>>3)*64 + c*16 + (k&7)*2
//   read:  lane l (n=l&15, hi=l>>4, col=n&3), slice ks ->
//          b128 at ks*256 + hi*64 + col*16     [quad same addr]
//   write: lane (w,hi,n): rows k0,k0+1, col; k0 = w*32 + t*16 + hi*4 + 2p
//          b32 at (w*4 + t*2 + (hi>>1))*64 + col*16 + ((hi&1)*4 + 2p)*2
//          (64 distinct dwords per wave -> conflict-free)
//
//   Light barrier (lgkmcnt only) + distance-2 xw prefetch into 4-slot cv
//   rotation (all indices compile-time).
// ---------------------------------------------------------------------------
__global__ __launch_bounds__(512, 2) void rnn_kernel(
    const float* __restrict__ xw, const float* __restrict__ W_hh,
    float* __restrict__ hsum_out) {
    const int tid = threadIdx.x;
    const int w = tid >> 6;  // wave 0..7, rows 32w..32w+31
    const int l = tid & 63;
    const int n = l & 15;    // A row / B col / C col (0..15)
    const int hi = l >> 4;   // k-group
    const int col = n & 3;   // real batch col within block
    const int d = n >> 2;    // duplicate index 0..3 (epilogue split)
    const int bbase = blockIdx.x * 4;
    const int rowbase = w * 32;

    __shared__ __attribute__((aligned(16))) unsigned char Hl[2][2048];
    char* lds = (char*)Hl;

    // ---- A fragments: W_hh rows rowbase..rowbase+31 as f16 (64 regs) ----
    h8_t a[2][8];
#pragma unroll
    for (int mt = 0; mt < 2; ++mt) {
        const float* wr = W_hh + (size_t)(rowbase + mt * 16 + n) * H_;
#pragma unroll
        for (int ks = 0; ks < 8; ++ks) {
            const float* wp = wr + ks * 32 + hi * 8;
            float4 f0 = *(const float4*)wp;
            float4 f1 = *(const float4*)(wp + 4);
            h8_t v;
            v[0] = (_Float16)f0.x; v[1] = (_Float16)f0.y;
            v[2] = (_Float16)f0.z; v[3] = (_Float16)f0.w;
            v[4] = (_Float16)f1.x; v[5] = (_Float16)f1.y;
            v[6] = (_Float16)f1.z; v[7] = (_Float16)f1.w;
            a[mt][ks] = v;
        }
    }

    // Epilogue assignment: tile t = d>>1, pair p = d&1 -> rows k0, k0+1
    // k0 = w*32 + t*16 + hi*4 + 2p
    const int t_ = d >> 1;
    const int p_ = d & 1;
    const int k0 = rowbase + t_ * 16 + hi * 4 + 2 * p_;
    // H'-write byte offset (buffer-relative), b32 covering k0, k0+1:
    const int wboff = (k0 >> 3) * 64 + col * 16 + (k0 & 7) * 2;
    // B-read base (buffer-relative); bf[ks] at CUR*2048 + rdbase + ks*256
    const int rdbase = hi * 64 + col * 16;

    // zero H buffer 0 (2 KB = 512 dwords)
    if (tid < 512) ((unsigned int*)Hl)[tid] = 0u;

    float2 hs;
    hs.x = 0.0f;
    hs.y = 0.0f;

    // per-lane xw base: xw[s][bbase+col][rowbase + mt*16 + hi*4 + r]
    const float* xwl = xw + (size_t)(bbase + col) * H_ + rowbase + hi * 4;
    // 4-slot rotation of xw-as-C-operand buffers (distance-2 prefetch)
    f32x4 cv[4][2];
    cv[0][0] = *(const f32x4*)(xwl);                  // s = 0
    cv[0][1] = *(const f32x4*)(xwl + 16);
    cv[1][0] = *(const f32x4*)(xwl + 16384);          // s = 1
    cv[1][1] = *(const f32x4*)(xwl + 16384 + 16);
    __syncthreads();  // zero-init visible

#define STEP(CUR, I, SBASE)                                                    \
    {                                                                          \
        int sp = (SBASE) + 2;                                                  \
        if (sp > S_ - 1) sp = S_ - 1;                                          \
        cv[(I + 2) & 3][0] = *(const f32x4*)(xwl + (size_t)sp * 16384);        \
        cv[(I + 2) & 3][1] = *(const f32x4*)(xwl + (size_t)sp * 16384 + 16);   \
        h8_t bf[8];                                                            \
        _Pragma("unroll") for (int ks = 0; ks < 8; ++ks)                       \
            bf[ks] = *(const h8_t*)(lds + (CUR)*2048 + rdbase + ks * 256);     \
        _Pragma("unroll") for (int ks = 0; ks < 8; ++ks) {                     \
            cv[I][0] = __builtin_amdgcn_mfma_f32_16x16x32_f16(                 \
                a[0][ks], bf[ks], cv[I][0], 0, 0, 0);                          \
            cv[I][1] = __builtin_amdgcn_mfma_f32_16x16x32_f16(                 \
                a[1][ks], bf[ks], cv[I][1], 0, 0, 0);                          \
        }                                                                      \
        {                                                                      \
            f32x4 sv = (t_ == 0) ? cv[I][0] : cv[I][1];                        \
            float e0 = (p_ == 0) ? sv[0] : sv[2];                              \
            float e1 = (p_ == 0) ? sv[1] : sv[3];                              \
            float h0 = fast_tanh(e0);                                          \
            float h1 = fast_tanh(e1);                                          \
            hs.x += h0;                                                        \
            hs.y += h1;                                                        \
            unsigned int pk = __builtin_bit_cast(                              \
                unsigned int, __builtin_amdgcn_cvt_pkrtz(h0, h1));             \
            *(unsigned int*)(lds + ((CUR) ^ 1) * 2048 + wboff) = pk;           \
        }                                                                      \
        asm volatile("s_waitcnt lgkmcnt(0)" ::: "memory");                     \
        __builtin_amdgcn_s_barrier();                                          \
    }

    for (int s = 0; s < S_; s += 4) {
        STEP(0, 0, s)
        STEP(1, 1, s + 1)
        STEP(0, 2, s + 2)
        STEP(1, 3, s + 3)
    }
#undef STEP

    // lane writes its 2 rows: k0, k0+1, col  (k0 even -> 8B aligned)
    {
        float2 o;
        o.x = hs.x;
        o.y = hs.y;
        *(float2*)(hsum_out + (size_t)(bbase + col) * H_ + k0) = o;
    }
}

// ---------------------------------------------------------------------------
// Kernel D: summed logits = hsum @ W_out^T + S*b_out, then log_softmax.
// ---------------------------------------------------------------------------
__global__ void out_kernel(const float* __restrict__ hsum,
                           const float* __restrict__ W_out,
                           const float* __restrict__ b_out,
                           float* __restrict__ out) {
    int b = threadIdx.x;
    if (b >= B_) return;
    float logits[C_];
#pragma unroll
    for (int c = 0; c < C_; ++c) {
        float acc = 0.0f;
        for (int k = 0; k < H_; ++k)
            acc = fmaf(hsum[b * H_ + k], W_out[c * H_ + k], acc);
        logits[c] = acc + (float)S_ * b_out[c];
    }
    float m = logits[0];
#pragma unroll
    for (int c = 1; c < C_; ++c) m = fmaxf(m, logits[c]);
    float sum = 0.0f;
#pragma unroll
    for (int c = 0; c < C_; ++c) sum += expf(logits[c] - m);
    float lse = logf(sum);
#pragma unroll
    for (int c = 0; c < C_; ++c) out[b * C_ + c] = logits[c] - m - lse;
}

// ---------------------------------------------------------------------------
extern "C" void kernel_launch(void* const* d_in, const int* in_sizes, int n_in,
                              void* d_out, int out_size, void* d_ws,
                              size_t ws_size, hipStream_t stream) {
    const int* idx = (const int*)d_in[0];
    const float* emb = (const float*)d_in[1];
    const float* W_ih = (const float*)d_in[2];
    const float* W_hh = (const float*)d_in[3];
    const float* b_ih = (const float*)d_in[4];
    const float* b_hh = (const float*)d_in[5];
    const float* W_out = (const float*)d_in[6];
    const float* b_out = (const float*)d_in[7];
    float* out = (float*)d_out;

    float* ws = (float*)d_ws;
    uint4* WB = (uint4*)ws;                    // 16*10*64 uint4 = 160 KB
    float* xw = ws + 40960;                    // S*B*H floats
    float* hsum = xw + (size_t)S_ * B_ * H_;   // B*H floats

    hipLaunchKernelGGL(wb_prep_kernel, dim3(40), dim3(256), 0, stream, W_ih,
                       WB);
    hipLaunchKernelGGL(xw_kernel, dim3((S_ * B_) / 64), dim3(512), 0, stream,
                       idx, emb, WB, b_ih, b_hh, xw);
    hipLaunchKernelGGL(rnn_kernel, dim3(16), dim3(512), 0, stream, xw, W_hh,
                       hsum);
    hipLaunchKernelGGL(out_kernel, dim3(1), dim3(64), 0, stream, hsum, W_out,
                       b_out, out);
}